// Round 1
// baseline (1738.161 us; speedup 1.0000x reference)
//
#include <hip/hip_runtime.h>
#include <hip/hip_bf16.h>

#define NHEADS 16
#define HDIM   64
#define MDIM   1024
#define NTOK   121
#define NBATCH 1024

typedef __attribute__((ext_vector_type(4))) float f32x4;
typedef __attribute__((ext_vector_type(4))) short s16x4;
typedef __attribute__((ext_vector_type(8))) short s16x8;

__device__ __forceinline__ short f2bf(float f) {
  unsigned u = __builtin_bit_cast(unsigned, f);
  u = (u + 0x7FFFu + ((u >> 16) & 1u)) >> 16;   // RNE f32 -> bf16
  return (short)u;
}

// ---------------------------------------------------------------------------
// Kernel 0: transpose+convert Wq/Wk/Wv (f32 [k][n]) -> bf16 Wt [n][k] in ws.
// Makes the B operand k-contiguous so the GEMMs can global_load_lds it.
// ---------------------------------------------------------------------------
__global__ __launch_bounds__(256) void kTransW(const float* __restrict__ Wq,
                                               const float* __restrict__ Wk,
                                               const float* __restrict__ Wv,
                                               short* __restrict__ Wt) {
  int bid = blockIdx.x;
  int m = bid >> 8, tile = bid & 255;
  int tr = tile >> 4, tc = tile & 15;        // tr: k-tile, tc: n-tile (64x64)
  const float* W = (m == 0) ? Wq : (m == 1) ? Wk : Wv;
  short* T = Wt + (size_t)m * (MDIM * MDIM);
  __shared__ float tl[64][68];               // pad 68 keeps 16B alignment
  int t = threadIdx.x;
  int c4 = t & 15, r0 = t >> 4;
#pragma unroll
  for (int i = 0; i < 4; ++i) {
    int kr = r0 + i * 16;
    f32x4 v = *(const f32x4*)(W + (size_t)(tr * 64 + kr) * MDIM + tc * 64 + c4 * 4);
    *(f32x4*)&tl[kr][c4 * 4] = v;
  }
  __syncthreads();
#pragma unroll
  for (int i = 0; i < 4; ++i) {
    int n = r0 + i * 16;
    s16x4 o;
    o.x = f2bf(tl[c4 * 4 + 0][n]);
    o.y = f2bf(tl[c4 * 4 + 1][n]);
    o.z = f2bf(tl[c4 * 4 + 2][n]);
    o.w = f2bf(tl[c4 * 4 + 3][n]);
    *(s16x4*)(T + (size_t)(tc * 64 + n) * MDIM + tr * 64 + c4 * 4) = o;
  }
}

// ---------------------------------------------------------------------------
// Shared GEMM core: C[128x128] = A[128(rows valid up to mrows) x 1024] * W^T tile.
// A: f32 global, reg-staged -> bf16 LDS, XOR-swizzled ((row&7)<<4).
// B: bf16 Wt [n][k], global_load_lds (16B) with pre-swizzled source chunks.
// 256 threads = 4 waves (2x2), wave tile 64x64, mfma 16x16x32 bf16.
// ---------------------------------------------------------------------------
__device__ __forceinline__ void gemm_core(const float* __restrict__ A, int mrows,
                                          const short* __restrict__ Wt, int c0,
                                          short* Alds, short* Blds,
                                          f32x4 acc[4][4], int t) {
  int wid = t >> 6, lane = t & 63;
  int wr = wid >> 1, wc = wid & 1;
  int li = lane & 15, lg = lane >> 4;
  int kq = t & 15, r0s = t >> 4;                 // A staging map
#pragma unroll
  for (int fm = 0; fm < 4; ++fm)
#pragma unroll
    for (int fn = 0; fn < 4; ++fn) acc[fm][fn] = (f32x4)0.0f;

  for (int kt = 0; kt < 16; ++kt) {
    int k0 = kt * 64;
    __syncthreads();                              // previous tile consumed
    // ---- stage A: 128 rows x 64 k, f32 -> bf16, swizzled
#pragma unroll
    for (int i = 0; i < 8; ++i) {
      int row = r0s + (i << 4);
      f32x4 v = (f32x4)0.0f;
      if (row < mrows) v = *(const f32x4*)(A + (size_t)row * MDIM + k0 + kq * 4);
      s16x4 b4;
      b4.x = f2bf(v.x); b4.y = f2bf(v.y); b4.z = f2bf(v.z); b4.w = f2bf(v.w);
      int byte = (row * 128 + kq * 8) ^ ((row & 7) << 4);
      *(s16x4*)((char*)Alds + byte) = b4;
    }
    // ---- stage B: cols [c0,c0+128), k [k0,k0+64), via global_load_lds.
    // LDS layout [col][64k] bf16; chunk j holds global chunk j^(col&7)
    // (pre-swizzled source) so reads can XOR-deswizzle for bank-conflict-free.
#pragma unroll
    for (int i = 0; i < 4; ++i) {
      int cl = wid * 32 + i * 8 + (lane >> 3);
      int jg = (lane & 7) ^ (cl & 7);
      const short* g = Wt + (size_t)(c0 + cl) * MDIM + k0 + jg * 8;
      short* lb = Blds + (wid * 32 + i * 8) * 64;   // wave-uniform base
      __builtin_amdgcn_global_load_lds((const __attribute__((address_space(1))) void*)g,
                                       (__attribute__((address_space(3))) void*)lb,
                                       16, 0, 0);
    }
    __syncthreads();                              // staging complete
    // ---- MFMA over the 64-k tile (2 x k=32 steps)
#pragma unroll
    for (int ks = 0; ks < 2; ++ks) {
      s16x8 af[4], bf[4];
      int kb = ks * 64 + lg * 16;                 // byte offset within row
#pragma unroll
      for (int fm = 0; fm < 4; ++fm) {
        int row = wr * 64 + fm * 16 + li;
        int byte = (row * 128 + kb) ^ ((row & 7) << 4);
        af[fm] = *(s16x8*)((char*)Alds + byte);
      }
#pragma unroll
      for (int fn = 0; fn < 4; ++fn) {
        int col = wc * 64 + fn * 16 + li;
        int byte = (col * 128 + kb) ^ ((col & 7) << 4);
        bf[fn] = *(s16x8*)((char*)Blds + byte);
      }
#pragma unroll
      for (int fm = 0; fm < 4; ++fm)
#pragma unroll
        for (int fn = 0; fn < 4; ++fn)
          acc[fm][fn] = __builtin_amdgcn_mfma_f32_16x16x32_bf16(af[fm], bf[fn],
                                                                acc[fm][fn], 0, 0, 0);
    }
  }
}

// ---------------------------------------------------------------------------
// q_proj = query @ Wq + bq  -> f32 into d_out's output region (scratch)
// ---------------------------------------------------------------------------
__global__ __launch_bounds__(256, 2) void kQProj(const float* __restrict__ query,
                                                 const short* __restrict__ WtQ,
                                                 const float* __restrict__ bq,
                                                 float* __restrict__ qproj) {
  __shared__ alignas(16) short Alds[128 * 64];
  __shared__ alignas(16) short Blds[128 * 64];
  int bid = blockIdx.x;
  int rt = bid >> 3, ct = bid & 7;
  f32x4 acc[4][4];
  int t = threadIdx.x;
  gemm_core(query + (size_t)rt * 128 * MDIM, 128, WtQ, ct * 128, Alds, Blds, acc, t);
  int wid = t >> 6, lane = t & 63;
  int wr = wid >> 1, wc = wid & 1, li = lane & 15, lg = lane >> 4;
#pragma unroll
  for (int fn = 0; fn < 4; ++fn) {
    int col = ct * 128 + wc * 64 + fn * 16 + li;
    float bqv = bq[col];
#pragma unroll
    for (int fm = 0; fm < 4; ++fm)
#pragma unroll
      for (int rr = 0; rr < 4; ++rr) {
        int row = rt * 128 + wr * 64 + fm * 16 + lg * 4 + rr;
        qproj[(size_t)row * MDIM + col] = acc[fm][fn][rr] + bqv;
      }
  }
}

// ---------------------------------------------------------------------------
// k-GEMM fused with scores + softmax -> writes weights [B,H,121] (f32, d_out)
// block = (batch b, col-tile ct of 128 = heads {2ct, 2ct+1})
// ---------------------------------------------------------------------------
__global__ __launch_bounds__(256, 2) void kScores(const float* __restrict__ key,
                                                  const short* __restrict__ WtK,
                                                  const float* __restrict__ bk,
                                                  const float* __restrict__ qproj,
                                                  float* __restrict__ weights) {
  __shared__ alignas(16) short Alds[128 * 64];
  __shared__ alignas(16) short Blds[128 * 64];
  __shared__ float s_lds[2][128];
  int bid = blockIdx.x;
  int lbid = (bid & 7) * 1024 + (bid >> 3);   // XCD-chunked: 8 ct-blocks of a b stay on one XCD
  int b = lbid >> 3, ct = lbid & 7;
  f32x4 acc[4][4];
  int t = threadIdx.x;
  gemm_core(key + (size_t)b * NTOK * MDIM, NTOK, WtK, ct * 128, Alds, Blds, acc, t);
  int wid = t >> 6, lane = t & 63;
  int wr = wid >> 1, wc = wid & 1, li = lane & 15, lg = lane >> 4;
  // scores[n] = sum_{d in head} (kproj + bk)[n,col] * q[col]; wave's 64 cols = 1 head
  float qv[4], bkv[4];
#pragma unroll
  for (int fn = 0; fn < 4; ++fn) {
    int col = ct * 128 + wc * 64 + fn * 16 + li;
    qv[fn]  = qproj[(size_t)b * MDIM + col];
    bkv[fn] = bk[col];
  }
#pragma unroll
  for (int fm = 0; fm < 4; ++fm)
#pragma unroll
    for (int rr = 0; rr < 4; ++rr) {
      float p = 0.f;
#pragma unroll
      for (int fn = 0; fn < 4; ++fn) p += (acc[fm][fn][rr] + bkv[fn]) * qv[fn];
      p += __shfl_xor(p, 1); p += __shfl_xor(p, 2);
      p += __shfl_xor(p, 4); p += __shfl_xor(p, 8);
      if (li == 0) {
        int n = wr * 64 + fm * 16 + lg * 4 + rr;
        s_lds[wc][n] = p;
      }
    }
  __syncthreads();
  // softmax per head: wave 0 -> head local 0, wave 1 -> head local 1
  if (wid < 2) {
    int hg = ct * 2 + wid;
    int n0 = lane, n1 = lane + 64;
    bool v0 = (n0 < NTOK), v1 = (n1 < NTOK);
    float w0, w1;
    if (hg == 0 || hg == 3) {                 // disturb heads: uniform weights
      w0 = 1.f / NTOK; w1 = 1.f / NTOK;
    } else {
      const float kinv = 1.f / 32.f;          // 1/sqrt(d*H)
      float s0 = v0 ? s_lds[wid][n0] * kinv : -1e30f;
      float s1 = v1 ? s_lds[wid][n1] * kinv : -1e30f;
      float m = fmaxf(s0, s1);
#pragma unroll
      for (int msk = 1; msk < 64; msk <<= 1) m = fmaxf(m, __shfl_xor(m, msk));
      float e0 = v0 ? __expf(s0 - m) : 0.f;
      float e1 = v1 ? __expf(s1 - m) : 0.f;
      float s = e0 + e1;
#pragma unroll
      for (int msk = 1; msk < 64; msk <<= 1) s += __shfl_xor(s, msk);
      float inv = 1.f / s;
      w0 = e0 * inv; w1 = e1 * inv;
    }
    float* wp = weights + ((size_t)b * NHEADS + hg) * NTOK;
    if (v0) wp[n0] = w0;
    if (v1) wp[n1] = w1;
  }
}

// ---------------------------------------------------------------------------
// v-GEMM fused with weighted reduction -> output [B, 1024] (f32, d_out)
// ---------------------------------------------------------------------------
__global__ __launch_bounds__(256, 2) void kOut(const float* __restrict__ value,
                                               const short* __restrict__ WtV,
                                               const float* __restrict__ bv,
                                               const float* __restrict__ weights,
                                               float* __restrict__ outp) {
  __shared__ alignas(16) short Alds[128 * 64];
  __shared__ alignas(16) short Blds[128 * 64];
  __shared__ float w_lds[2][128];
  __shared__ float outacc[128];
  int bid = blockIdx.x;
  int lbid = (bid & 7) * 1024 + (bid >> 3);
  int b = lbid >> 3, ct = lbid & 7;
  int t = threadIdx.x;
  {
    int hl = t >> 7, n = t & 127;
    w_lds[hl][n] = (n < NTOK)
        ? weights[((size_t)b * NHEADS + ct * 2 + hl) * NTOK + n] : 0.f;
  }
  f32x4 acc[4][4];
  gemm_core(value + (size_t)b * NTOK * MDIM, NTOK, WtV, ct * 128, Alds, Blds, acc, t);
  int wid = t >> 6, lane = t & 63;
  int wr = wid >> 1, wc = wid & 1, li = lane & 15, lg = lane >> 4;
  float sum4[4] = {0.f, 0.f, 0.f, 0.f};
#pragma unroll
  for (int fm = 0; fm < 4; ++fm)
#pragma unroll
    for (int rr = 0; rr < 4; ++rr) {
      int n = wr * 64 + fm * 16 + lg * 4 + rr;
      float wv = w_lds[wc][n];                  // 0 for n>=121
#pragma unroll
      for (int fn = 0; fn < 4; ++fn) sum4[fn] += acc[fm][fn][rr] * wv;
    }
#pragma unroll
  for (int fn = 0; fn < 4; ++fn) {
    sum4[fn] += __shfl_xor(sum4[fn], 16);
    sum4[fn] += __shfl_xor(sum4[fn], 32);
  }
  if (wr == 0 && lane < 16) {
#pragma unroll
    for (int fn = 0; fn < 4; ++fn) outacc[wc * 64 + fn * 16 + lane] = sum4[fn];
  }
  __syncthreads();
  if (wr == 1 && lane < 16) {
#pragma unroll
    for (int fn = 0; fn < 4; ++fn) outacc[wc * 64 + fn * 16 + lane] += sum4[fn];
  }
  __syncthreads();
  if (t < 128) {
    int col = ct * 128 + t;
    outp[(size_t)b * MDIM + col] = outacc[t] + bv[col];
  }
}

// ---------------------------------------------------------------------------
extern "C" void kernel_launch(void* const* d_in, const int* in_sizes, int n_in,
                              void* d_out, int out_size, void* d_ws, size_t ws_size,
                              hipStream_t stream) {
  const float* query = (const float*)d_in[0];
  const float* key   = (const float*)d_in[1];
  const float* value = (const float*)d_in[2];
  const float* Wq    = (const float*)d_in[3];
  const float* bq    = (const float*)d_in[4];
  const float* Wk    = (const float*)d_in[5];
  const float* bk    = (const float*)d_in[6];
  const float* Wv    = (const float*)d_in[7];
  const float* bv    = (const float*)d_in[8];

  float* out     = (float*)d_out;
  float* weights = out + (size_t)NBATCH * MDIM;  // d_out[1048576:]
  float* qproj   = out;                          // reuse output region as scratch
  short* Wt      = (short*)d_ws;                 // 3 x 1M bf16 = 6 MB

  hipLaunchKernelGGL(kTransW, dim3(768),  dim3(256), 0, stream, Wq, Wk, Wv, Wt);
  hipLaunchKernelGGL(kQProj,  dim3(64),   dim3(256), 0, stream, query, Wt, bq, qproj);
  hipLaunchKernelGGL(kScores, dim3(8192), dim3(256), 0, stream,
                     key, Wt + (size_t)MDIM * MDIM, bk, qproj, weights);
  hipLaunchKernelGGL(kOut,    dim3(8192), dim3(256), 0, stream,
                     value, Wt + 2 * (size_t)MDIM * MDIM, bv, weights, out);
}

// Round 2
// 863.048 us; speedup vs baseline: 2.0140x; 2.0140x over previous
//
#include <hip/hip_runtime.h>
#include <hip/hip_bf16.h>

#define NHEADS 16
#define HDIM   64
#define MDIM   1024
#define NTOK   121
#define NBATCH 1024

typedef __attribute__((ext_vector_type(4))) float f32x4;
typedef __attribute__((ext_vector_type(4))) short s16x4;
typedef __attribute__((ext_vector_type(8))) short s16x8;

__device__ __forceinline__ short f2bf(float f) {
  unsigned u = __builtin_bit_cast(unsigned, f);
  u = (u + 0x7FFFu + ((u >> 16) & 1u)) >> 16;   // RNE f32 -> bf16
  return (short)u;
}

// ---------------------------------------------------------------------------
// Kernel 0: transpose+convert Wq/Wk/Wv (f32 [k][n]) -> bf16 Wt [n][k] in ws.
// ---------------------------------------------------------------------------
__global__ __launch_bounds__(256) void kTransW(const float* __restrict__ Wq,
                                               const float* __restrict__ Wk,
                                               const float* __restrict__ Wv,
                                               short* __restrict__ Wt) {
  int bid = blockIdx.x;
  int m = bid >> 8, tile = bid & 255;
  int tr = tile >> 4, tc = tile & 15;        // tr: k-tile, tc: n-tile (64x64)
  const float* W = (m == 0) ? Wq : (m == 1) ? Wk : Wv;
  short* T = Wt + (size_t)m * (MDIM * MDIM);
  __shared__ float tl[64][68];
  int t = threadIdx.x;
  int c4 = t & 15, r0 = t >> 4;
#pragma unroll
  for (int i = 0; i < 4; ++i) {
    int kr = r0 + i * 16;
    f32x4 v = *(const f32x4*)(W + (size_t)(tr * 64 + kr) * MDIM + tc * 64 + c4 * 4);
    *(f32x4*)&tl[kr][c4 * 4] = v;
  }
  __syncthreads();
#pragma unroll
  for (int i = 0; i < 4; ++i) {
    int n = r0 + i * 16;
    s16x4 o;
    o.x = f2bf(tl[c4 * 4 + 0][n]);
    o.y = f2bf(tl[c4 * 4 + 1][n]);
    o.z = f2bf(tl[c4 * 4 + 2][n]);
    o.w = f2bf(tl[c4 * 4 + 3][n]);
    *(s16x4*)(T + (size_t)(tc * 64 + n) * MDIM + tr * 64 + c4 * 4) = o;
  }
}

// ---------------------------------------------------------------------------
// Kernel 0b: bulk f32 -> bf16 convert (for key / value A-operands).
// n16 = element count / 16. Zeroes an 8192-element pad after the tensor so
// the GEMM's 128-row staging may over-read the final batch safely.
// ---------------------------------------------------------------------------
__global__ __launch_bounds__(256) void kConv(const float* __restrict__ src,
                                             short* __restrict__ dst, long n16) {
  long stride = (long)gridDim.x * 256;
  for (long i = (long)blockIdx.x * 256 + threadIdx.x; i < n16; i += stride) {
    const f32x4* s = (const f32x4*)src + i * 4;
    f32x4 a = s[0], b = s[1], c = s[2], d = s[3];
    s16x8 o0, o1;
    o0[0] = f2bf(a.x); o0[1] = f2bf(a.y); o0[2] = f2bf(a.z); o0[3] = f2bf(a.w);
    o0[4] = f2bf(b.x); o0[5] = f2bf(b.y); o0[6] = f2bf(b.z); o0[7] = f2bf(b.w);
    o1[0] = f2bf(c.x); o1[1] = f2bf(c.y); o1[2] = f2bf(c.z); o1[3] = f2bf(c.w);
    o1[4] = f2bf(d.x); o1[5] = f2bf(d.y); o1[6] = f2bf(d.z); o1[7] = f2bf(d.w);
    ((s16x8*)dst)[i * 2]     = o0;
    ((s16x8*)dst)[i * 2 + 1] = o1;
  }
  if (blockIdx.x == 0) {
    for (int j = threadIdx.x; j < 8192; j += 256) dst[n16 * 16 + j] = 0;
  }
}

// ---------------------------------------------------------------------------
// Shared GEMM core: C[128x128] = A[128 x 1024] * Wt-tile^T.
// ABF16=true : A bf16 [row][1024], staged via global_load_lds (pre-swizzled src)
// ABF16=false: A f32, reg-staged with convert (fallback / small qproj)
// B: bf16 Wt [n][k], global_load_lds (16B) with pre-swizzled source chunks.
// 256 threads = 4 waves (2x2), wave tile 64x64, mfma 16x16x32 bf16.
// LDS layout for both operands: [row][64] bf16, chunk j holds global chunk
// j^(row&7); reads XOR-deswizzle -> bank-conflict-free ds_read_b128.
// ---------------------------------------------------------------------------
template <bool ABF16>
__device__ __forceinline__ void gemm_core(const float* Af, const short* Ab, int mrows,
                                          const short* __restrict__ Wt, int c0,
                                          short* Alds, short* Blds,
                                          f32x4 acc[4][4], int t) {
  int wid = t >> 6, lane = t & 63;
  int wr = wid >> 1, wc = wid & 1;
  int li = lane & 15, lg = lane >> 4;
  int kq = t & 15, r0s = t >> 4;
#pragma unroll
  for (int fm = 0; fm < 4; ++fm)
#pragma unroll
    for (int fn = 0; fn < 4; ++fn) acc[fm][fn] = (f32x4)0.0f;

  for (int kt = 0; kt < 16; ++kt) {
    int k0 = kt * 64;
    __syncthreads();                              // previous tile consumed
    if constexpr (ABF16) {
      // ---- stage A via global_load_lds (same pattern as B)
#pragma unroll
      for (int i = 0; i < 4; ++i) {
        int rl = wid * 32 + i * 8 + (lane >> 3);
        int jg = (lane & 7) ^ (rl & 7);
        const short* g = Ab + (size_t)rl * MDIM + k0 + jg * 8;
        short* lb = Alds + (wid * 32 + i * 8) * 64;   // wave-uniform base
        __builtin_amdgcn_global_load_lds((const __attribute__((address_space(1))) void*)g,
                                         (__attribute__((address_space(3))) void*)lb,
                                         16, 0, 0);
      }
    } else {
      // ---- stage A: reg-stage f32 -> bf16, swizzled write
#pragma unroll
      for (int i = 0; i < 8; ++i) {
        int row = r0s + (i << 4);
        f32x4 v = (f32x4)0.0f;
        if (row < mrows) v = *(const f32x4*)(Af + (size_t)row * MDIM + k0 + kq * 4);
        s16x4 b4;
        b4.x = f2bf(v.x); b4.y = f2bf(v.y); b4.z = f2bf(v.z); b4.w = f2bf(v.w);
        int byte = (row * 128 + kq * 8) ^ ((row & 7) << 4);
        *(s16x4*)((char*)Alds + byte) = b4;
      }
    }
    // ---- stage B
#pragma unroll
    for (int i = 0; i < 4; ++i) {
      int cl = wid * 32 + i * 8 + (lane >> 3);
      int jg = (lane & 7) ^ (cl & 7);
      const short* g = Wt + (size_t)(c0 + cl) * MDIM + k0 + jg * 8;
      short* lb = Blds + (wid * 32 + i * 8) * 64;
      __builtin_amdgcn_global_load_lds((const __attribute__((address_space(1))) void*)g,
                                       (__attribute__((address_space(3))) void*)lb,
                                       16, 0, 0);
    }
    __syncthreads();                              // staging complete
    // ---- MFMA over the 64-k tile (2 x k=32 steps)
#pragma unroll
    for (int ks = 0; ks < 2; ++ks) {
      s16x8 af[4], bf[4];
      int kb = ks * 64 + lg * 16;
#pragma unroll
      for (int fm = 0; fm < 4; ++fm) {
        int row = wr * 64 + fm * 16 + li;
        int byte = (row * 128 + kb) ^ ((row & 7) << 4);
        af[fm] = *(s16x8*)((char*)Alds + byte);
      }
#pragma unroll
      for (int fn = 0; fn < 4; ++fn) {
        int col = wc * 64 + fn * 16 + li;
        int byte = (col * 128 + kb) ^ ((col & 7) << 4);
        bf[fn] = *(s16x8*)((char*)Blds + byte);
      }
#pragma unroll
      for (int fm = 0; fm < 4; ++fm)
#pragma unroll
        for (int fn = 0; fn < 4; ++fn)
          acc[fm][fn] = __builtin_amdgcn_mfma_f32_16x16x32_bf16(af[fm], bf[fn],
                                                                acc[fm][fn], 0, 0, 0);
    }
  }
}

// ---------------------------------------------------------------------------
// q_proj = query @ Wq + bq  -> f32 into d_out's output region (scratch)
// ---------------------------------------------------------------------------
__global__ __launch_bounds__(256, 4) void kQProj(const float* __restrict__ query,
                                                 const short* __restrict__ WtQ,
                                                 const float* __restrict__ bq,
                                                 float* __restrict__ qproj) {
  __shared__ alignas(16) short Alds[128 * 64];
  __shared__ alignas(16) short Blds[128 * 64];
  int bid = blockIdx.x;
  int rt = bid >> 3, ct = bid & 7;
  f32x4 acc[4][4];
  int t = threadIdx.x;
  gemm_core<false>(query + (size_t)rt * 128 * MDIM, nullptr, 128, WtQ, ct * 128,
                   Alds, Blds, acc, t);
  int wid = t >> 6, lane = t & 63;
  int wr = wid >> 1, wc = wid & 1, li = lane & 15, lg = lane >> 4;
#pragma unroll
  for (int fn = 0; fn < 4; ++fn) {
    int col = ct * 128 + wc * 64 + fn * 16 + li;
    float bqv = bq[col];
#pragma unroll
    for (int fm = 0; fm < 4; ++fm)
#pragma unroll
      for (int rr = 0; rr < 4; ++rr) {
        int row = rt * 128 + wr * 64 + fm * 16 + lg * 4 + rr;
        qproj[(size_t)row * MDIM + col] = acc[fm][fn][rr] + bqv;
      }
  }
}

// ---------------------------------------------------------------------------
// k-GEMM fused with scores + softmax -> writes weights [B,H,121] (f32, d_out)
// ---------------------------------------------------------------------------
template <bool ABF16>
__global__ __launch_bounds__(256, 4) void kScores(const float* __restrict__ keyf,
                                                  const short* __restrict__ keyb,
                                                  const short* __restrict__ WtK,
                                                  const float* __restrict__ bk,
                                                  const float* __restrict__ qproj,
                                                  float* __restrict__ weights) {
  __shared__ alignas(16) short Alds[128 * 64];
  __shared__ alignas(16) short Blds[128 * 64];
  __shared__ float s_lds[2][128];
  int bid = blockIdx.x;
  int lbid = (bid & 7) * 1024 + (bid >> 3);   // XCD-chunked: one batch's 8 ct stay on one XCD
  int b = lbid >> 3, ct = lbid & 7;
  f32x4 acc[4][4];
  int t = threadIdx.x;
  gemm_core<ABF16>(ABF16 ? nullptr : keyf + (size_t)b * NTOK * MDIM,
                   ABF16 ? keyb + (size_t)b * NTOK * MDIM : nullptr,
                   NTOK, WtK, ct * 128, Alds, Blds, acc, t);
  int wid = t >> 6, lane = t & 63;
  int wr = wid >> 1, wc = wid & 1, li = lane & 15, lg = lane >> 4;
  float qv[4], bkv[4];
#pragma unroll
  for (int fn = 0; fn < 4; ++fn) {
    int col = ct * 128 + wc * 64 + fn * 16 + li;
    qv[fn]  = qproj[(size_t)b * MDIM + col];
    bkv[fn] = bk[col];
  }
#pragma unroll
  for (int fm = 0; fm < 4; ++fm)
#pragma unroll
    for (int rr = 0; rr < 4; ++rr) {
      float p = 0.f;
#pragma unroll
      for (int fn = 0; fn < 4; ++fn) p += (acc[fm][fn][rr] + bkv[fn]) * qv[fn];
      p += __shfl_xor(p, 1); p += __shfl_xor(p, 2);
      p += __shfl_xor(p, 4); p += __shfl_xor(p, 8);
      if (li == 0) {
        int n = wr * 64 + fm * 16 + lg * 4 + rr;
        s_lds[wc][n] = p;
      }
    }
  __syncthreads();
  if (wid < 2) {
    int hg = ct * 2 + wid;
    int n0 = lane, n1 = lane + 64;
    bool v0 = (n0 < NTOK), v1 = (n1 < NTOK);
    float w0, w1;
    if (hg == 0 || hg == 3) {                 // disturb heads: uniform weights
      w0 = 1.f / NTOK; w1 = 1.f / NTOK;
    } else {
      const float kinv = 1.f / 32.f;          // 1/sqrt(d*H)
      float s0 = v0 ? s_lds[wid][n0] * kinv : -1e30f;
      float s1 = v1 ? s_lds[wid][n1] * kinv : -1e30f;
      float m = fmaxf(s0, s1);
#pragma unroll
      for (int msk = 1; msk < 64; msk <<= 1) m = fmaxf(m, __shfl_xor(m, msk));
      float e0 = v0 ? __expf(s0 - m) : 0.f;
      float e1 = v1 ? __expf(s1 - m) : 0.f;
      float s = e0 + e1;
#pragma unroll
      for (int msk = 1; msk < 64; msk <<= 1) s += __shfl_xor(s, msk);
      float inv = 1.f / s;
      w0 = e0 * inv; w1 = e1 * inv;
    }
    float* wp = weights + ((size_t)b * NHEADS + hg) * NTOK;
    if (v0) wp[n0] = w0;
    if (v1) wp[n1] = w1;
  }
}

// ---------------------------------------------------------------------------
// v-GEMM fused with weighted reduction -> output [B, 1024] (f32, d_out)
// ---------------------------------------------------------------------------
template <bool ABF16>
__global__ __launch_bounds__(256, 4) void kOut(const float* __restrict__ valuef,
                                               const short* __restrict__ valueb,
                                               const short* __restrict__ WtV,
                                               const float* __restrict__ bv,
                                               const float* __restrict__ weights,
                                               float* __restrict__ outp) {
  __shared__ alignas(16) short Alds[128 * 64];
  __shared__ alignas(16) short Blds[128 * 64];
  __shared__ float w_lds[2][128];
  __shared__ float outacc[128];
  int bid = blockIdx.x;
  int lbid = (bid & 7) * 1024 + (bid >> 3);
  int b = lbid >> 3, ct = lbid & 7;
  int t = threadIdx.x;
  {
    int hl = t >> 7, n = t & 127;
    w_lds[hl][n] = (n < NTOK)
        ? weights[((size_t)b * NHEADS + ct * 2 + hl) * NTOK + n] : 0.f;
  }
  f32x4 acc[4][4];
  gemm_core<ABF16>(ABF16 ? nullptr : valuef + (size_t)b * NTOK * MDIM,
                   ABF16 ? valueb + (size_t)b * NTOK * MDIM : nullptr,
                   NTOK, WtV, ct * 128, Alds, Blds, acc, t);
  int wid = t >> 6, lane = t & 63;
  int wr = wid >> 1, wc = wid & 1, li = lane & 15, lg = lane >> 4;
  float sum4[4] = {0.f, 0.f, 0.f, 0.f};
#pragma unroll
  for (int fm = 0; fm < 4; ++fm)
#pragma unroll
    for (int rr = 0; rr < 4; ++rr) {
      int n = wr * 64 + fm * 16 + lg * 4 + rr;
      float wv = w_lds[wc][n];                  // 0 for n>=121 (and garbage rows)
#pragma unroll
      for (int fn = 0; fn < 4; ++fn) sum4[fn] += acc[fm][fn][rr] * wv;
    }
#pragma unroll
  for (int fn = 0; fn < 4; ++fn) {
    sum4[fn] += __shfl_xor(sum4[fn], 16);
    sum4[fn] += __shfl_xor(sum4[fn], 32);
  }
  if (wr == 0 && lane < 16) {
#pragma unroll
    for (int fn = 0; fn < 4; ++fn) outacc[wc * 64 + fn * 16 + lane] = sum4[fn];
  }
  __syncthreads();
  if (wr == 1 && lane < 16) {
#pragma unroll
    for (int fn = 0; fn < 4; ++fn) outacc[wc * 64 + fn * 16 + lane] += sum4[fn];
  }
  __syncthreads();
  if (t < 128) {
    int col = ct * 128 + t;
    outp[(size_t)b * MDIM + col] = outacc[t] + bv[col];
  }
}

// ---------------------------------------------------------------------------
extern "C" void kernel_launch(void* const* d_in, const int* in_sizes, int n_in,
                              void* d_out, int out_size, void* d_ws, size_t ws_size,
                              hipStream_t stream) {
  const float* query = (const float*)d_in[0];
  const float* key   = (const float*)d_in[1];
  const float* value = (const float*)d_in[2];
  const float* Wq    = (const float*)d_in[3];
  const float* bq    = (const float*)d_in[4];
  const float* Wk    = (const float*)d_in[5];
  const float* bk    = (const float*)d_in[6];
  const float* Wv    = (const float*)d_in[7];
  const float* bv    = (const float*)d_in[8];

  float* out     = (float*)d_out;
  float* weights = out + (size_t)NBATCH * MDIM;
  float* qproj   = out;                          // output region reused as scratch

  const size_t WT_BYTES  = 3ull * MDIM * MDIM * 2;              // 6 MB
  const long   NELEM     = (long)NBATCH * NTOK * MDIM;          // 126,877,696
  const size_t KV_BYTES  = (size_t)NELEM * 2 + 16384;           // + zero pad
  const size_t NEED      = WT_BYTES + 2 * KV_BYTES;             // ~490 MB

  short* Wt = (short*)d_ws;
  bool fast = (ws_size >= NEED);

  kTransW<<<dim3(768), dim3(256), 0, stream>>>(Wq, Wk, Wv, Wt);

  if (fast) {
    short* Kb = (short*)((char*)d_ws + WT_BYTES);
    short* Vb = (short*)((char*)d_ws + WT_BYTES + KV_BYTES);
    kConv<<<dim3(2048), dim3(256), 0, stream>>>(key,   Kb, NELEM / 16);
    kConv<<<dim3(2048), dim3(256), 0, stream>>>(value, Vb, NELEM / 16);
    kQProj<<<dim3(64), dim3(256), 0, stream>>>(query, Wt, bq, qproj);
    kScores<true><<<dim3(8192), dim3(256), 0, stream>>>(
        nullptr, Kb, Wt + (size_t)MDIM * MDIM, bk, qproj, weights);
    kOut<true><<<dim3(8192), dim3(256), 0, stream>>>(
        nullptr, Vb, Wt + 2 * (size_t)MDIM * MDIM, bv, weights, out);
  } else {
    kQProj<<<dim3(64), dim3(256), 0, stream>>>(query, Wt, bq, qproj);
    kScores<false><<<dim3(8192), dim3(256), 0, stream>>>(
        key, nullptr, Wt + (size_t)MDIM * MDIM, bk, qproj, weights);
    kOut<false><<<dim3(8192), dim3(256), 0, stream>>>(
        value, nullptr, Wt + 2 * (size_t)MDIM * MDIM, bv, weights, out);
  }
}